// Round 6
// baseline (6358.385 us; speedup 1.0000x reference)
//
#include <hip/hip_runtime.h>

typedef _Float16 f16;
typedef _Float16 half8 __attribute__((ext_vector_type(8)));
typedef float f32x4 __attribute__((ext_vector_type(4)));
typedef float f32x2 __attribute__((ext_vector_type(2)));

#define TT 512
#define HID 1024

__device__ __forceinline__ half8 cvt8(f32x4 lo, f32x4 hi) {
  half8 r;
  r[0]=(f16)lo[0]; r[1]=(f16)lo[1]; r[2]=(f16)lo[2]; r[3]=(f16)lo[3];
  r[4]=(f16)hi[0]; r[5]=(f16)hi[1]; r[6]=(f16)hi[2]; r[7]=(f16)hi[3];
  return r;
}
// device-scope coherent ops: write through / read past L2 (never flush caches)
__device__ __forceinline__ void st_sc_u32(unsigned* p, unsigned v) {
  asm volatile("global_store_dword %0, %1, off sc0 sc1" :: "v"(p), "v"(v) : "memory");
}
__device__ __forceinline__ unsigned ld_sc_u32(const unsigned* p) {
  unsigned v;
  asm volatile("global_load_dword %0, %1, off sc0 sc1\n\ts_waitcnt vmcnt(0)"
               : "=v"(v) : "v"(p) : "memory");
  return v;
}
__device__ __forceinline__ void spinFlag(const unsigned* p) {
  int gd = 0;
  while (ld_sc_u32(p) == 0u) { __builtin_amdgcn_s_sleep(1); if (++gd > (1<<20)) break; }
}
__device__ __forceinline__ float sigm(float x)  { return 1.f/(1.f + __expf(-x)); }
__device__ __forceinline__ float ftanh(float x) { return 1.f - 2.f/(1.f + __expf(2.f*x)); }

// x f32 -> f16 (layout kept [B][T][D])
__global__ void init_misc(const float* __restrict__ x, f16* __restrict__ xh) {
  size_t i = ((size_t)blockIdx.x*256 + threadIdx.x)*8;
  f32x4 a = *(const f32x4*)(x+i);
  f32x4 b = *(const f32x4*)(x+i+4);
  *(half8*)(xh+i) = cvt8(a,b);
}

// Persistent pipelined TSGRU. 256 WGs x 512 thr (8 waves). WG = (layer, 16 cols).
// Wave (g,kq): weights W[g][3 gates][16 cols][K-quarter kq] persistent in 96 VGPRs.
// A-operands load DIRECTLY global->VGPR in MFMA fragment layout (no LDS staging,
// no staging barriers): per chunk kc, aF[m] = A[m*16+(lane&15)][kc*128+kq*32+u*8],
// software-pipelined 3 chunks deep; compiler tracks vmcnt on the registers.
// Only 2 barriers/step (around the PART reduce + gate). g=0 waves poll upstream
// flags only; g=1 waves poll own-layer flags only (concurrent polls).
// hd precomputed by gate t-1 into 8-plane rotation HD[l][t&7] (no staleness window,
// no decay math on the load path).
__global__ __launch_bounds__(512, 2) void tsgru_k(
    const float* __restrict__ dtp, const float* __restrict__ Wih,
    const float* __restrict__ Whh, const float* __restrict__ bih,
    const float* __restrict__ bhh, const float* __restrict__ tau,
    const f16* __restrict__ xh, f16* __restrict__ H, f16* __restrict__ HD,
    unsigned* __restrict__ flags, float* __restrict__ out) {
  extern __shared__ char lds[];
  float* PART = (float*)lds;   // [24 slices][1088] f32 = 104448 B (col-major pad-68)

  const int tid = threadIdx.x, lane = tid & 63, wv = tid >> 6;
  const int g = wv >> 2, kq = wv & 3;
  const int wg = blockIdx.x, layer = wg >> 6, wgl = wg & 63, col0 = wgl*16;

  // ---- persistent weights in VGPRs (f32 source, convert inline; read once)
  const float* Wsrc = (g ? Whh : Wih) + (size_t)layer*3072*HID;
  const int wrow = col0 + (lane & 15);
  const int kfr = kq*32 + ((lane>>4)&3)*8;     // f16 k-offset within a 128-chunk
  half8 bW[3][8];
  #pragma unroll
  for (int q=0;q<3;q++)
    #pragma unroll
    for (int kc=0;kc<8;kc++) {
      const float* p = Wsrc + (size_t)(q*HID + wrow)*HID + kc*128 + kfr;
      bW[q][kc] = cvt8(*(const f32x4*)p, *(const f32x4*)(p+4));
    }

  // ---- gate constants in registers
  const int gb = tid >> 3, gc2 = (tid & 7)*2;
  float biR[2],biZ[2],biN[2],bhR[2],bhZ[2],bhN[2],ni[2];
  #pragma unroll
  for (int e=0;e<2;e++) {
    const int c = col0 + gc2 + e;
    biR[e]=bih[layer*3072+c]; biZ[e]=bih[layer*3072+1024+c]; biN[e]=bih[layer*3072+2048+c];
    bhR[e]=bhh[layer*3072+c]; bhZ[e]=bhh[layer*3072+1024+c]; bhN[e]=bhh[layer*3072+2048+c];
    ni[e] = -1.0f / log1pf(expf(tau[layer*HID + c]));
  }

  // ---- A-operand geometry for this wave
  const f16* AgPlane = (layer==0) ? xh : H + (size_t)(layer-1)*TT*65536;
  const size_t ars = g ? (size_t)HID : ((layer==0) ? (size_t)TT*HID : (size_t)HID);
  f16* HDl = HD + (size_t)layer*8*65536;       // [8][64][1024] rotation
  unsigned* flagOwn = flags + (size_t)layer*TT*64;
  const unsigned* flagUp = flags + (size_t)(layer>0 ? layer-1 : 0)*TT*64;

  float hdv0 = 0.f, hdv1 = 0.f;

  for (int t = 0; t < TT; ++t) {
    const float dtg1 = (t < TT-1) ? dtp[gb*TT + t + 1] : 0.f;

    // ---- group-specific point-to-point waits (concurrent across wave groups)
    if (g) {
      if (t > 0 && lane != wgl) spinFlag(flagOwn + (size_t)(t-1)*64 + lane);
    } else if (layer > 0) {
      spinFlag(flagUp + (size_t)t*64 + lane);
    }

    // ---- per-wave A base pointers (MFMA fragment layout, direct from global)
    const f16* Abase = g ? (HDl + (size_t)(t&7)*65536)
                         : ((layer==0) ? xh + (size_t)t*HID
                                       : AgPlane + (size_t)t*65536);
    const f16* pr[4];
    #pragma unroll
    for (int m=0;m<4;m++)
      pr[m] = Abase + (size_t)(m*16 + (lane&15))*ars + kfr;

    // ---- K-loop: 8 chunks of 128, A 3-deep reg pipeline, 12 MFMA/chunk
    half8 aF[3][4];
    #pragma unroll
    for (int c=0;c<3;c++)
      #pragma unroll
      for (int m=0;m<4;m++)
        aF[c][m] = *(const half8*)(pr[m] + c*128);

    f32x4 acc[4][3];
    #pragma unroll
    for (int m=0;m<4;m++) {
      acc[m][0]=(f32x4){0.f,0.f,0.f,0.f}; acc[m][1]=acc[m][0]; acc[m][2]=acc[m][0];
    }

    #pragma unroll
    for (int kc=0;kc<8;kc++) {
      #pragma unroll
      for (int m=0;m<4;m++) {
        const half8 a = aF[kc%3][m];
        acc[m][0] = __builtin_amdgcn_mfma_f32_16x16x32_f16(a, bW[0][kc], acc[m][0],0,0,0);
        acc[m][1] = __builtin_amdgcn_mfma_f32_16x16x32_f16(a, bW[1][kc], acc[m][1],0,0,0);
        acc[m][2] = __builtin_amdgcn_mfma_f32_16x16x32_f16(a, bW[2][kc], acc[m][2],0,0,0);
      }
      if (kc < 5) {
        #pragma unroll
        for (int m=0;m<4;m++)
          aF[(kc+3)%3][m] = *(const half8*)(pr[m] + (kc+3)*128);
      }
    }

    // ---- partial sums -> LDS, col-major pad-68 (bank-friendly b128 stores)
    {
      float* Pb = PART + (size_t)((g*4+kq)*3)*1088 + (lane&15)*68 + ((lane>>4)&3)*4;
      #pragma unroll
      for (int qg=0;qg<3;qg++)
        #pragma unroll
        for (int m=0;m<4;m++)
          *(f32x4*)(Pb + qg*1088 + m*16) = acc[m][qg];
    }
    asm volatile("s_waitcnt lgkmcnt(0)" ::: "memory");
    __builtin_amdgcn_s_barrier();

    // ---- gates: thread -> (batch gb, cols gc2,gc2+1); hd kept in regs + HD plane
    {
      float hv[2];
      #pragma unroll
      for (int e=0;e<2;e++) {
        const int pb = (gc2+e)*68 + gb;
        float sx0=0,sx1=0,sx2=0,sh0=0,sh1=0,sh2=0;
        #pragma unroll
        for (int k2=0;k2<4;k2++) {
          const float* Px = PART + (size_t)(k2*3)*1088 + pb;
          sx0 += Px[0]; sx1 += Px[1088]; sx2 += Px[2176];
          const float* Ph = PART + (size_t)((4+k2)*3)*1088 + pb;
          sh0 += Ph[0]; sh1 += Ph[1088]; sh2 += Ph[2176];
        }
        const float hdv = e ? hdv1 : hdv0;
        const float r = sigm(sx0 + biR[e] + sh0 + bhR[e]);
        const float z = sigm(sx1 + biZ[e] + sh1 + bhZ[e]);
        const float n = ftanh(sx2 + biN[e] + r*(sh2 + bhN[e]));
        hv[e] = (1.f - z)*n + z*hdv;
      }
      union { f16 h[2]; unsigned u; } pk;
      if (layer < 3) {
        pk.h[0]=(f16)hv[0]; pk.h[1]=(f16)hv[1];
        st_sc_u32((unsigned*)(H + ((size_t)layer*TT + t)*65536 + gb*HID + col0 + gc2), pk.u);
      } else {
        f32x2 v; v[0]=hv[0]; v[1]=hv[1];
        *(f32x2*)(out + ((size_t)gb*TT + t)*HID + col0 + gc2) = v;
      }
      if (t < TT-1) {
        const float hd0 = hv[0]*__expf(dtg1*ni[0]);
        const float hd1 = hv[1]*__expf(dtg1*ni[1]);
        pk.h[0]=(f16)hd0; pk.h[1]=(f16)hd1;
        st_sc_u32((unsigned*)(HDl + (size_t)((t+1)&7)*65536 + gb*HID + col0 + gc2), pk.u);
        hdv0 = hd0; hdv1 = hd1;
      }
    }
    asm volatile("s_waitcnt vmcnt(0) lgkmcnt(0)" ::: "memory");  // stores coherent
    __builtin_amdgcn_s_barrier();
    if (tid == 0) st_sc_u32(flagOwn + (size_t)t*64 + wgl, 1u);
  }
}

extern "C" void kernel_launch(void* const* d_in, const int* in_sizes, int n_in,
                              void* d_out, int out_size, void* d_ws, size_t ws_size,
                              hipStream_t stream) {
  const float* x   = (const float*)d_in[0];
  const float* dtp = (const float*)d_in[1];
  const float* Wih = (const float*)d_in[2];
  const float* Whh = (const float*)d_in[3];
  const float* bih = (const float*)d_in[4];
  const float* bhh = (const float*)d_in[5];
  const float* tau = (const float*)d_in[6];
  float* out = (float*)d_out;
  char* ws = (char*)d_ws;

  // ws: xh [64][512][1024] f16 (67,108,864) | H [3][512][64][1024] f16 (201,326,592)
  //   | HD [4][8][64][1024] f16 (4,194,304) | flags [4][512][64] u32 (524,288)
  //   -> total 273,154,048 B
  f16* xh = (f16*)ws;
  f16* H  = (f16*)(ws + 67108864);
  f16* HD = (f16*)(ws + 268435456);
  unsigned* flags = (unsigned*)(ws + 268435456 + 4194304);

  (void)hipMemsetAsync(flags, 0, 524288, stream);
  (void)hipMemsetAsync(HD, 0, 4194304, stream);     // hd[l][plane 0] = 0 (t=0)
  init_misc<<<16384, 256, 0, stream>>>(x, xh);
  const int ldsBytes = 104448;                      // PART only; >80KB -> 1 WG/CU
  (void)hipFuncSetAttribute((const void*)tsgru_k, hipFuncAttributeMaxDynamicSharedMemorySize, ldsBytes);
  tsgru_k<<<256, 512, ldsBytes, stream>>>(dtp, Wih, Whh, bih, bhh, tau, xh, H, HD, flags, out);
}

// Round 7
// 5055.103 us; speedup vs baseline: 1.2578x; 1.2578x over previous
//
#include <hip/hip_runtime.h>

typedef _Float16 f16;
typedef _Float16 half8 __attribute__((ext_vector_type(8)));
typedef float f32x4 __attribute__((ext_vector_type(4)));
typedef float f32x2 __attribute__((ext_vector_type(2)));

#define TT 512
#define HID 1024

__device__ __forceinline__ half8 cvt8(f32x4 lo, f32x4 hi) {
  half8 r;
  r[0]=(f16)lo[0]; r[1]=(f16)lo[1]; r[2]=(f16)lo[2]; r[3]=(f16)lo[3];
  r[4]=(f16)hi[0]; r[5]=(f16)hi[1]; r[6]=(f16)hi[2]; r[7]=(f16)hi[3];
  return r;
}
// device-scope coherent ops: write through / read past L2 (never flush caches)
__device__ __forceinline__ void st_sc_u32(unsigned* p, unsigned v) {
  asm volatile("global_store_dword %0, %1, off sc0 sc1" :: "v"(p), "v"(v) : "memory");
}
__device__ __forceinline__ unsigned ld_sc_u32(const unsigned* p) {
  unsigned v;
  asm volatile("global_load_dword %0, %1, off sc0 sc1\n\ts_waitcnt vmcnt(0)"
               : "=v"(v) : "v"(p) : "memory");
  return v;
}
__device__ __forceinline__ void spinFlag(const unsigned* p) {
  int gd = 0;
  while (ld_sc_u32(p) == 0u) { __builtin_amdgcn_s_sleep(1); if (++gd > (1<<20)) break; }
}
__device__ __forceinline__ float sigm(float x)  { return 1.f/(1.f + __expf(-x)); }
__device__ __forceinline__ float ftanh(float x) { return 1.f - 2.f/(1.f + __expf(2.f*x)); }

// x [B][T][D] f32 -> xh [T][64 seg][64 b][16 c] f16 (WG-major plane layout)
__global__ void init_misc(const float* __restrict__ x, f16* __restrict__ xh) {
  size_t idx = (size_t)blockIdx.x*256 + threadIdx.x;
  size_t i = idx*8;
  int d = (int)(i & 1023);
  size_t bt = i >> 10;
  int t = (int)(bt & 511), b = (int)(bt >> 9);
  f32x4 a = *(const f32x4*)(x+i);
  f32x4 c4 = *(const f32x4*)(x+i+4);
  int s = d >> 4, c = d & 15;
  *(half8*)(xh + (((size_t)t*64 + s)*64 + b)*16 + c) = cvt8(a,c4);
}

// Persistent pipelined TSGRU. 256 WGs x 512 thr (8 waves). WG = (layer, 16 cols).
// Wave wv owns K-chunk [wv*128,(wv+1)*128) of BOTH GEMMs: bW[2][3][4] = 96 VGPRs.
// Per step: gx phase (upstream-gated, 12 MFMA/wave) -> PART -> gx sums to regs;
// own-flag poll (all waves) -> gh phase (12 MFMA/wave, A issued right after poll)
// -> PART -> gate. All h/hd planes WG-major [seg][b][16] so producer stores are
// contiguous full-line blocks (no LLC false sharing). HD = 32-plane rotation.
__global__ __launch_bounds__(512, 2) void tsgru_k(
    const float* __restrict__ dtp, const float* __restrict__ Wih,
    const float* __restrict__ Whh, const float* __restrict__ bih,
    const float* __restrict__ bhh, const float* __restrict__ tau,
    const f16* __restrict__ xh, f16* __restrict__ H, f16* __restrict__ HD,
    unsigned* __restrict__ flags, float* __restrict__ out) {
  extern __shared__ char lds[];
  float* PART = (float*)lds;   // [24 slices][1088] f32 = 104448 B (col-major pad-68)

  const int tid = threadIdx.x, lane = tid & 63, wv = tid >> 6;
  const int wg = blockIdx.x, layer = wg >> 6, wgl = wg & 63, col0 = wgl*16;
  const int u = (lane >> 4) & 3;

  // ---- persistent weights in VGPRs: both GEMMs, this wave's 128-K chunk
  const float* WihL = Wih + (size_t)layer*3072*HID;
  const float* WhhL = Whh + (size_t)layer*3072*HID;
  const int wcol = col0 + (lane & 15);
  half8 bW[2][3][4];
  #pragma unroll
  for (int g=0;g<2;g++)
    #pragma unroll
    for (int q=0;q<3;q++)
      #pragma unroll
      for (int ks=0;ks<4;ks++) {
        const float* p = (g ? WhhL : WihL) + (size_t)(q*HID + wcol)*HID + wv*128 + ks*32 + u*8;
        bW[g][q][ks] = cvt8(*(const f32x4*)p, *(const f32x4*)(p+4));
      }

  // ---- gate constants in registers
  const int gb = tid >> 3, gc2 = (tid & 7)*2;
  float biR[2],biZ[2],biN[2],bhR[2],bhZ[2],bhN[2],ni[2];
  #pragma unroll
  for (int e=0;e<2;e++) {
    const int c = col0 + gc2 + e;
    biR[e]=bih[layer*3072+c]; biZ[e]=bih[layer*3072+1024+c]; biN[e]=bih[layer*3072+2048+c];
    bhR[e]=bhh[layer*3072+c]; bhZ[e]=bhh[layer*3072+1024+c]; bhN[e]=bhh[layer*3072+2048+c];
    ni[e] = -1.0f / log1pf(expf(tau[layer*HID + c]));
  }

  // A-fragment offset in a WG-major plane: seg = wv*8 + ks*2 + (u>>1)
  const int baseA = (wv*8 + (u>>1))*1024 + (lane&15)*16 + (u&1)*8;

  const f16* gxBase = (layer==0) ? xh : H + (size_t)(layer-1)*TT*65536;
  f16* HDl = HD + (size_t)layer*32*65536;
  unsigned* flagOwn = flags + (size_t)layer*TT*64;
  const unsigned* flagUp = flags + (size_t)(layer>0 ? layer-1 : 0)*TT*64;

  float hdv0 = 0.f, hdv1 = 0.f;

  for (int t = 0; t < TT; ++t) {
    const float dtg1 = (t < TT-1) ? dtp[gb*TT + t + 1] : 0.f;

    // ---- upstream gate: wave 0 polls, barrier releases the WG
    if (layer > 0 && wv == 0) spinFlag(flagUp + (size_t)t*64 + lane);
    __builtin_amdgcn_s_barrier();                        // bar0

    // ======== GX phase (off the recurrence) ========
    const f16* gxP = gxBase + (size_t)t*65536;
    half8 aF[2][4];
    #pragma unroll
    for (int ks=0;ks<2;ks++)
      #pragma unroll
      for (int m=0;m<4;m++)
        aF[ks][m] = *(const half8*)(gxP + baseA + ks*2048 + m*256);

    f32x4 acc[4][3];
    #pragma unroll
    for (int m=0;m<4;m++) { acc[m][0]=(f32x4){0.f,0.f,0.f,0.f}; acc[m][1]=acc[m][0]; acc[m][2]=acc[m][0]; }
    #pragma unroll
    for (int ks=0;ks<4;ks++) {
      #pragma unroll
      for (int m=0;m<4;m++) {
        const half8 a = aF[ks&1][m];
        acc[m][0] = __builtin_amdgcn_mfma_f32_16x16x32_f16(a, bW[0][0][ks], acc[m][0],0,0,0);
        acc[m][1] = __builtin_amdgcn_mfma_f32_16x16x32_f16(a, bW[0][1][ks], acc[m][1],0,0,0);
        acc[m][2] = __builtin_amdgcn_mfma_f32_16x16x32_f16(a, bW[0][2][ks], acc[m][2],0,0,0);
      }
      if (ks<2) {
        #pragma unroll
        for (int m=0;m<4;m++)
          aF[ks&1][m] = *(const half8*)(gxP + baseA + (ks+2)*2048 + m*256);
      }
    }
    {
      float* Pb = PART + (size_t)(wv*3)*1088 + (lane&15)*68 + u*4;
      #pragma unroll
      for (int q=0;q<3;q++)
        #pragma unroll
        for (int m=0;m<4;m++)
          *(f32x4*)(Pb + q*1088 + m*16) = acc[m][q];
    }
    asm volatile("s_waitcnt lgkmcnt(0)" ::: "memory");
    __builtin_amdgcn_s_barrier();                        // bar1: gx partials ready

    // gx sums -> registers (survive through gh phase)
    float sx0[2]={0.f,0.f}, sx1[2]={0.f,0.f}, sx2[2]={0.f,0.f};
    #pragma unroll
    for (int e=0;e<2;e++) {
      const int pb = (gc2+e)*68 + gb;
      #pragma unroll
      for (int w8=0;w8<8;w8++) {
        const float* P = PART + (size_t)(w8*3)*1088 + pb;
        sx0[e] += P[0]; sx1[e] += P[1088]; sx2[e] += P[2176];
      }
    }

    // ======== own-recurrence gate + GH phase ========
    if (t > 0 && lane != wgl) spinFlag(flagOwn + (size_t)(t-1)*64 + lane);
    const f16* ghP = HDl + (size_t)(t & 31)*65536;
    if (t > 0) {
      #pragma unroll
      for (int ks=0;ks<2;ks++)
        #pragma unroll
        for (int m=0;m<4;m++)
          aF[ks][m] = *(const half8*)(ghP + baseA + ks*2048 + m*256);   // issue early
    }
    asm volatile("s_waitcnt lgkmcnt(0)" ::: "memory");   // my gx reads done
    __builtin_amdgcn_s_barrier();                        // bar2: PART reusable

    #pragma unroll
    for (int m=0;m<4;m++) { acc[m][0]=(f32x4){0.f,0.f,0.f,0.f}; acc[m][1]=acc[m][0]; acc[m][2]=acc[m][0]; }
    if (t > 0) {
      #pragma unroll
      for (int ks=0;ks<4;ks++) {
        #pragma unroll
        for (int m=0;m<4;m++) {
          const half8 a = aF[ks&1][m];
          acc[m][0] = __builtin_amdgcn_mfma_f32_16x16x32_f16(a, bW[1][0][ks], acc[m][0],0,0,0);
          acc[m][1] = __builtin_amdgcn_mfma_f32_16x16x32_f16(a, bW[1][1][ks], acc[m][1],0,0,0);
          acc[m][2] = __builtin_amdgcn_mfma_f32_16x16x32_f16(a, bW[1][2][ks], acc[m][2],0,0,0);
        }
        if (ks<2) {
          #pragma unroll
          for (int m=0;m<4;m++)
            aF[ks&1][m] = *(const half8*)(ghP + baseA + (ks+2)*2048 + m*256);
        }
      }
    }
    {
      float* Pb = PART + (size_t)(wv*3)*1088 + (lane&15)*68 + u*4;
      #pragma unroll
      for (int q=0;q<3;q++)
        #pragma unroll
        for (int m=0;m<4;m++)
          *(f32x4*)(Pb + q*1088 + m*16) = acc[m][q];
    }
    asm volatile("s_waitcnt lgkmcnt(0)" ::: "memory");
    __builtin_amdgcn_s_barrier();                        // bar3: gh partials ready

    // ---- gate: thread -> (batch gb, cols gc2,gc2+1); fp32 math, hd in regs
    {
      float hv[2];
      #pragma unroll
      for (int e=0;e<2;e++) {
        const int pb = (gc2+e)*68 + gb;
        float sh0=0.f, sh1=0.f, sh2=0.f;
        #pragma unroll
        for (int w8=0;w8<8;w8++) {
          const float* P = PART + (size_t)(w8*3)*1088 + pb;
          sh0 += P[0]; sh1 += P[1088]; sh2 += P[2176];
        }
        const float hdv = e ? hdv1 : hdv0;
        const float r = sigm(sx0[e] + biR[e] + sh0 + bhR[e]);
        const float z = sigm(sx1[e] + biZ[e] + sh1 + bhZ[e]);
        const float n = ftanh(sx2[e] + biN[e] + r*(sh2 + bhN[e]));
        hv[e] = (1.f - z)*n + z*hdv;
      }
      union { f16 h[2]; unsigned uu; } pk;
      const size_t slot = (size_t)(wgl*64 + gb)*16 + gc2;     // WG-major plane slot
      if (layer < 3) {
        pk.h[0]=(f16)hv[0]; pk.h[1]=(f16)hv[1];
        st_sc_u32((unsigned*)(H + ((size_t)layer*TT + t)*65536 + slot), pk.uu);
      } else {
        f32x2 v; v[0]=hv[0]; v[1]=hv[1];
        *(f32x2*)(out + ((size_t)gb*TT + t)*HID + col0 + gc2) = v;
      }
      if (t < TT-1) {
        const float hd0 = hv[0]*__expf(dtg1*ni[0]);
        const float hd1 = hv[1]*__expf(dtg1*ni[1]);
        pk.h[0]=(f16)hd0; pk.h[1]=(f16)hd1;
        st_sc_u32((unsigned*)(HDl + (size_t)((t+1)&31)*65536 + slot), pk.uu);
        hdv0 = hd0; hdv1 = hd1;
      }
    }
    asm volatile("s_waitcnt vmcnt(0) lgkmcnt(0)" ::: "memory");  // stores coherent
    __builtin_amdgcn_s_barrier();                        // bar4
    if (tid == 0) st_sc_u32(flagOwn + (size_t)t*64 + wgl, 1u);
  }
}

extern "C" void kernel_launch(void* const* d_in, const int* in_sizes, int n_in,
                              void* d_out, int out_size, void* d_ws, size_t ws_size,
                              hipStream_t stream) {
  const float* x   = (const float*)d_in[0];
  const float* dtp = (const float*)d_in[1];
  const float* Wih = (const float*)d_in[2];
  const float* Whh = (const float*)d_in[3];
  const float* bih = (const float*)d_in[4];
  const float* bhh = (const float*)d_in[5];
  const float* tau = (const float*)d_in[6];
  float* out = (float*)d_out;
  char* ws = (char*)d_ws;

  // ws: xh [512][64][64][16] f16 (67,108,864) | H [3][512][64*64*16] f16 (201,326,592)
  //   | HD [4][32][64*64*16] f16 (16,777,216) | flags [4][512][64] u32 (524,288)
  //   -> total 285,736,960 B
  f16* xh = (f16*)ws;
  f16* H  = (f16*)(ws + 67108864);
  f16* HD = (f16*)(ws + 268435456);
  unsigned* flags = (unsigned*)(ws + 268435456 + 16777216);

  (void)hipMemsetAsync(flags, 0, 524288, stream);
  init_misc<<<16384, 256, 0, stream>>>(x, xh);
  const int ldsBytes = 104448;                      // PART only; >80KB -> 1 WG/CU
  (void)hipFuncSetAttribute((const void*)tsgru_k, hipFuncAttributeMaxDynamicSharedMemorySize, ldsBytes);
  tsgru_k<<<256, 512, ldsBytes, stream>>>(dtp, Wih, Whh, bih, bhh, tau, xh, H, HD, flags, out);
}